// Round 1
// baseline (411.094 us; speedup 1.0000x reference)
//
#include <hip/hip_runtime.h>
#include <math.h>

// ---------------------------------------------------------------------------
// AdaptiveWindowAttention — round 7: deep-pipelined 256x128 GEMM core
// (8-wave, BK=64, 2 phases/K-tile, counted vmcnt(6), raw s_barrier, setprio),
// K-half-plane LDS with superrow XOR swizzle staged via global_load_lds with
// pre-swizzled global source. Grids quantize perfectly (768 / 256 blocks).
// B=2 S=2048 EMB=2048 H=16 D=128; window in [64,256]
// ---------------------------------------------------------------------------

#define S_LEN 2048
#define EMB 2048
#define HEADS 16
#define HDIM 128
#define NT 20          // attn: 320-key span = NT*16
#define PSTR 336       // attn: P row stride in f16 (320 + 16 pad)

typedef _Float16 f16x8 __attribute__((ext_vector_type(8)));
typedef _Float16 f16x4 __attribute__((ext_vector_type(4)));
typedef float f32x4 __attribute__((ext_vector_type(4)));

__device__ __forceinline__ void gld16(const void* g, void* l) {
    __builtin_amdgcn_global_load_lds(
        (const __attribute__((address_space(1))) unsigned int*)g,
        (__attribute__((address_space(3))) unsigned int*)l, 16, 0, 0);
}

// ---------------- rope tables (cos,sin interleaved) ----------------
__global__ void rope_table(float2* __restrict__ cstab) {
    int s = blockIdx.x;
    int d = threadIdx.x;
    int j = d & 63;
    double inv = pow(10000.0, -(double)j / 64.0);
    double ang = (double)s * inv;
    cstab[s * HDIM + d] = make_float2((float)cos(ang), (float)sin(ang));
}

// ---------------- batch stats + fused x->f16 (float4, 4 cols/thread) --------
__global__ __launch_bounds__(256) void col_reduce(const float* __restrict__ x,
                                                  float* __restrict__ xmean_acc,
                                                  double* __restrict__ scal,
                                                  _Float16* __restrict__ x16) {
    int b = blockIdx.z;
    int cg = blockIdx.x;     // 2 column groups of 1024
    int sg = blockIdx.y;     // 64 row chunks of 32
    int e4 = cg * 256 + threadIdx.x;          // float4 column index
    const size_t base = ((size_t)b * S_LEN + sg * 32) * EMB;
    const float4* xb = (const float4*)(x + base) + e4;
    f16x4* xo = (f16x4*)(x16 + base) + e4;
    double cs0 = 0.0, cs1 = 0.0, cs2 = 0.0, cs3 = 0.0;
    double cq = 0.0;
    for (int s = 0; s < 32; ++s) {
        float4 v = xb[(size_t)s * (EMB / 4)];
        f16x4 o;
        o.x = (_Float16)v.x; o.y = (_Float16)v.y;
        o.z = (_Float16)v.z; o.w = (_Float16)v.w;
        xo[(size_t)s * (EMB / 4)] = o;
        cs0 += v.x; cs1 += v.y; cs2 += v.z; cs3 += v.w;
        cq += (double)v.x * v.x + (double)v.y * v.y +
              (double)v.z * v.z + (double)v.w * v.w;
    }
    float* xm = xmean_acc + b * EMB + e4 * 4;
    atomicAdd(xm + 0, (float)cs0);
    atomicAdd(xm + 1, (float)cs1);
    atomicAdd(xm + 2, (float)cs2);
    atomicAdd(xm + 3, (float)cs3);
    __shared__ double rs[256], rq[256];
    rs[threadIdx.x] = cs0 + cs1 + cs2 + cs3;
    rq[threadIdx.x] = cq;
    __syncthreads();
    for (int off = 128; off > 0; off >>= 1) {
        if (threadIdx.x < off) {
            rs[threadIdx.x] += rs[threadIdx.x + off];
            rq[threadIdx.x] += rq[threadIdx.x + off];
        }
        __syncthreads();
    }
    if (threadIdx.x == 0) {
        atomicAdd(&scal[b], rs[0]);
        atomicAdd(&scal[2 + b], rq[0]);
    }
}

__global__ __launch_bounds__(256) void hidden_kernel(const float* __restrict__ xmean_acc,
                                                     const float* __restrict__ wc1,
                                                     float* __restrict__ hidden) {
    int j = blockIdx.x;
    int b = blockIdx.y;
    const float* xm = xmean_acc + b * EMB;
    const float* wr = wc1 + (size_t)j * EMB;
    double acc = 0.0;
    for (int k = threadIdx.x; k < EMB; k += 256)
        acc += (double)xm[k] * (double)wr[k];
    __shared__ double red[256];
    red[threadIdx.x] = acc;
    __syncthreads();
    for (int off = 128; off > 0; off >>= 1) {
        if (threadIdx.x < off) red[threadIdx.x] += red[threadIdx.x + off];
        __syncthreads();
    }
    if (threadIdx.x == 0) {
        double z = red[0] * (1.0 / 2048.0);
        hidden[b * 512 + j] = (float)(z / (1.0 + exp(-z)));
    }
}

__global__ __launch_bounds__(512) void window_kernel(const float* __restrict__ hidden,
                                                     const float* __restrict__ wc2,
                                                     const double* __restrict__ scal,
                                                     int* __restrict__ wout) {
    __shared__ double red[512];
    __shared__ double wfs[2];
    for (int b = 0; b < 2; ++b) {
        red[threadIdx.x] = (double)hidden[b * 512 + threadIdx.x] * (double)wc2[threadIdx.x];
        __syncthreads();
        for (int off = 256; off > 0; off >>= 1) {
            if (threadIdx.x < off) red[threadIdx.x] += red[threadIdx.x + off];
            __syncthreads();
        }
        if (threadIdx.x == 0) {
            double pre = red[0];
            double learned = 1.0 / (1.0 + exp(-pre));
            const double N = (double)S_LEN * (double)EMB;
            double sum = scal[b], sq = scal[2 + b];
            double var = (sq - sum * sum / N) / (N - 1.0);
            double vn = 1.0 / (1.0 + exp(-(var * 10.0 - 5.0)));
            double comp = 0.5 * (vn + learned);
            wfs[b] = 64.0 + comp * 192.0;
        }
        __syncthreads();
    }
    if (threadIdx.x == 0) {
        float wf = (float)(0.5 * (wfs[0] + wfs[1]));
        int w = (int)wf;
        if (w > S_LEN) w = S_LEN;
        if (w < 64) w = 64;
        *wout = w;
    }
}

// ---------------- f32 -> f16 conversion (both weights, one launch) ----------
#define NQKV4 3145728   // 3*2048*2048/4
#define NOUT4 1048576   // 2048*2048/4
__global__ __launch_bounds__(256) void cvt_weights(const float* __restrict__ wqkv,
                                                   const float* __restrict__ wout,
                                                   _Float16* __restrict__ d_qkv,
                                                   _Float16* __restrict__ d_out) {
    int i = blockIdx.x * 256 + threadIdx.x;
    const float4* s;
    f16x4* d;
    if (i < NQKV4) {
        s = (const float4*)wqkv + i;
        d = (f16x4*)d_qkv + i;
    } else {
        s = (const float4*)wout + (i - NQKV4);
        d = (f16x4*)d_out + (i - NQKV4);
    }
    float4 v = *s;
    f16x4 o;
    o.x = (_Float16)v.x; o.y = (_Float16)v.y;
    o.z = (_Float16)v.z; o.w = (_Float16)v.w;
    *d = o;
}

// ---------------------------------------------------------------------------
// Deep-pipelined GEMM core: BM=256 BN=128 BK=64, 512 threads = 8 waves (4x2),
// per-wave 64x64 output (acc[4][4] f32x4).
//
// LDS: per (buf, khalf) a 16KB A-plane (256 rows x 32 k) and 8KB B-plane
// (128 rows x 32 k). Plane layout: superrow sr = row>>1 (128B = 8 chunks of
// 16B); logical chunk g = (row&1)*4 + (k>>3) stored at g ^ (sr&7).
// global_load_lds writes linearly (wave base + lane*16B); the XOR is applied
// to the per-lane GLOBAL source address, so read-side ds_read_b128 with the
// same XOR sees 2 lanes/16B-slot everywhere (free, m136).
//
// Ring: phase(kt,ks=0) stages Kh1(kt+1)->buf^1; phase(kt,ks=1) stages
// Kh0(kt+2)->buf. Each staged region's readers finished one trailing barrier
// earlier; each wave's vmcnt(6) before the trailing barrier guarantees (via
// the barrier) that data read 2 phases later has landed chip-wide.
// ---------------------------------------------------------------------------
#define NKT 32   // 2048 / 64

#define STAGE(bufc, khc, koff)                                              \
    gld16(aS0 + (koff), &As[bufc][khc][wv * 512]);                          \
    gld16(aS1 + (koff), &As[bufc][khc][(8 + wv) * 512]);                    \
    gld16(bS + (koff), &Bs[bufc][khc][wv * 512]);

#define VM6 asm volatile("s_waitcnt vmcnt(6)" ::: "memory");
#define VM3 asm volatile("s_waitcnt vmcnt(3)" ::: "memory");
#define VM0 asm volatile("s_waitcnt vmcnt(0)" ::: "memory");
#define VMX

#define PHASE(bufc, ksc, VM, ...)                                           \
    {                                                                       \
        f16x8 af[4], bf[4];                                                 \
        _Pragma("unroll")                                                   \
        for (int i_ = 0; i_ < 4; ++i_)                                      \
            af[i_] = *(const f16x8*)&As[bufc][ksc][aoff + i_ * 512];        \
        _Pragma("unroll")                                                   \
        for (int j_ = 0; j_ < 4; ++j_)                                      \
            bf[j_] = *(const f16x8*)&Bs[bufc][ksc][boff + j_ * 512];        \
        __VA_ARGS__                                                         \
        __builtin_amdgcn_sched_barrier(0);                                  \
        __builtin_amdgcn_s_barrier();                                       \
        asm volatile("s_waitcnt lgkmcnt(0)" ::: "memory");                  \
        __builtin_amdgcn_sched_barrier(0);                                  \
        __builtin_amdgcn_s_setprio(1);                                      \
        _Pragma("unroll")                                                   \
        for (int i_ = 0; i_ < 4; ++i_)                                      \
            _Pragma("unroll")                                               \
            for (int j_ = 0; j_ < 4; ++j_)                                  \
                acc[i_][j_] = __builtin_amdgcn_mfma_f32_16x16x32_f16(       \
                    af[i_], bf[j_], acc[i_][j_], 0, 0, 0);                  \
        __builtin_amdgcn_s_setprio(0);                                      \
        __builtin_amdgcn_sched_barrier(0);                                  \
        VM                                                                  \
        __builtin_amdgcn_s_barrier();                                       \
        __builtin_amdgcn_sched_barrier(0);                                  \
    }

#define GEMM256_CORE(An, Wn)                                                \
    __shared__ __align__(16) _Float16 As[2][2][8192];                       \
    __shared__ __align__(16) _Float16 Bs[2][2][4096];                       \
    const int tid = threadIdx.x;                                            \
    const int lane = tid & 63;                                              \
    const int wv = tid >> 6;                                                \
    const int wm = wv >> 1, wn = wv & 1;                                    \
    const int m0 = blockIdx.y * 256;                                        \
    const int n0 = blockIdx.x * 128;                                        \
    /* staging: per-lane pre-swizzled global source */                      \
    const int g = (lane & 7) ^ (lane >> 3);                                 \
    const int rb = 2 * (lane >> 3) + (g >> 2);                              \
    const int kq = (g & 3) * 8;                                             \
    const _Float16* aS0 = An + (size_t)(m0 + wv * 16 + rb) * EMB + kq;      \
    const _Float16* aS1 = aS0 + (size_t)128 * EMB;                          \
    const _Float16* bS = Wn + (size_t)(n0 + wv * 16 + rb) * EMB + kq;       \
    /* fragment read offsets (f16 units within a plane) */                  \
    const int frow = lane & 15, fgrp = lane >> 4;                           \
    const int srl = frow >> 1;                                              \
    const int cst = (((frow & 1) << 2) + fgrp) ^ srl;                       \
    const int aoff = (wm * 32 + srl) * 64 + cst * 8;                        \
    const int boff = (wn * 32 + srl) * 64 + cst * 8;                        \
    f32x4 acc[4][4] = {};                                                   \
    /* prologue: Kh0(0), Kh1(0), Kh0(1); first 3 loads must land */         \
    STAGE(0, 0, 0)                                                          \
    STAGE(0, 1, 32)                                                         \
    STAGE(1, 0, 64)                                                         \
    VM6                                                                     \
    __builtin_amdgcn_s_barrier();                                           \
    __builtin_amdgcn_sched_barrier(0);                                      \
    for (int kt = 0; kt < NKT - 2; kt += 2) {                               \
        const int kb = kt * 64;                                             \
        PHASE(0, 0, VM6, STAGE(1, 1, kb + 96))                              \
        PHASE(0, 1, VM6, STAGE(0, 0, kb + 128))                             \
        PHASE(1, 0, VM6, STAGE(0, 1, kb + 160))                             \
        PHASE(1, 1, VM6, STAGE(1, 0, kb + 192))                             \
    }                                                                       \
    PHASE(0, 0, VM6, STAGE(1, 1, 2016))                                     \
    PHASE(0, 1, VM3)                                                        \
    PHASE(1, 0, VM0)                                                        \
    PHASE(1, 1, VMX)                                                        \
    const int colbase = lane & 15;                                          \
    const int rowoff = (lane >> 4) * 4;

// qkv epilogue: rope fused -> q16/k16 f16 (B,H,S,D); v -> f16 (B,H,D,S)
__global__ __launch_bounds__(512, 2) void gemm_qkv_f16(const _Float16* __restrict__ An,
                                                       const _Float16* __restrict__ Wn,
                                                       _Float16* __restrict__ q16,
                                                       _Float16* __restrict__ k16,
                                                       _Float16* __restrict__ vt,
                                                       const float2* __restrict__ cstab) {
    GEMM256_CORE(An, Wn)
    const int which = n0 >> 11;
    const int h = (n0 >> 7) & 15;
    if (which == 2) {
#pragma unroll
        for (int i = 0; i < 4; ++i) {
#pragma unroll
            for (int j = 0; j < 4; ++j) {
                const int d = wn * 64 + j * 16 + colbase;
                int m = m0 + wm * 64 + i * 16 + rowoff;  // 4 consecutive rows
                int b = m >> 11, s = m & 2047;
                f16x4 o;
#pragma unroll
                for (int r = 0; r < 4; ++r) o[r] = (_Float16)acc[i][j][r];
                *(f16x4*)&vt[(((size_t)b * HEADS + h) * HDIM + d) * S_LEN + s] = o;
            }
        }
    } else {
        _Float16* dst = which == 0 ? q16 : k16;
        const float sgn = (colbase & 1) ? 1.f : -1.f;   // rotate_half sign
#pragma unroll
        for (int i = 0; i < 4; ++i) {
#pragma unroll
            for (int j = 0; j < 4; ++j) {
                const int d = wn * 64 + j * 16 + colbase;
#pragma unroll
                for (int r = 0; r < 4; ++r) {
                    int m = m0 + wm * 64 + i * 16 + rowoff + r;
                    int b = m >> 11, s = m & 2047;
                    float a = acc[i][j][r];
                    float p = __shfl_xor(a, 1, 64);      // partner: d^1, same s
                    float2 cs = cstab[(size_t)s * HDIM + d];
                    float o = fmaf(a, cs.x, sgn * p * cs.y);
                    dst[(((size_t)b * HEADS + h) * S_LEN + s) * HDIM + d] = (_Float16)o;
                }
            }
        }
    }
}

__global__ __launch_bounds__(512, 2) void gemm_out_f16(const _Float16* __restrict__ An,
                                                       const _Float16* __restrict__ Wn,
                                                       float* __restrict__ C) {
    GEMM256_CORE(An, Wn)
#pragma unroll
    for (int i = 0; i < 4; ++i) {
#pragma unroll
        for (int j = 0; j < 4; ++j) {
            const int n = n0 + wn * 64 + j * 16 + colbase;
#pragma unroll
            for (int r = 0; r < 4; ++r) {
                int m = m0 + wm * 64 + i * 16 + rowoff + r;
                C[(size_t)m * EMB + n] = acc[i][j][r];
            }
        }
    }
}

// ---------------- MFMA attention ----------------
__global__ __launch_bounds__(256) void attn_mfma(const _Float16* __restrict__ q16,
                                                 const _Float16* __restrict__ k16,
                                                 const _Float16* __restrict__ v16t,
                                                 _Float16* __restrict__ ob,
                                                 const int* __restrict__ wptr) {
    const int q0 = blockIdx.x * 64;
    const int h = blockIdx.y;
    const int b = blockIdx.z;
    const int tid = threadIdx.x;
    const int lane = tid & 63;
    const int wv = tid >> 6;
    const int w = *wptr;

    __shared__ _Float16 Pl[4][16 * PSTR];
    _Float16* Pw = Pl[wv];

    const int kstart = q0 - 256;
    int ntlo_w = (257 - w) >> 4;
    int ntlo_n = q0 < 256 ? ((256 - q0) >> 4) : 0;
    const int ntlo = ntlo_w > ntlo_n ? ntlo_w : ntlo_n;

    const int frow = lane & 15;
    const int fgrp = lane >> 4;
    const int fcol = fgrp * 8;

    const size_t bh = (size_t)b * HEADS + h;
    const _Float16* Qp = q16 + (bh * S_LEN + q0 + wv * 16 + frow) * HDIM + fcol;
    const _Float16* Kb = k16 + bh * S_LEN * HDIM;
    const _Float16* Vt = v16t + bh * HDIM * S_LEN;

    f16x8 aq[4];
#pragma unroll
    for (int ks = 0; ks < 4; ++ks) aq[ks] = *(const f16x8*)(Qp + ks * 32);

    // ---- QK^T ----
    f32x4 accs[NT];
#pragma unroll
    for (int nt = 0; nt < NT; ++nt) accs[nt] = (f32x4){0.f, 0.f, 0.f, 0.f};
#pragma unroll
    for (int nt = 0; nt < NT; ++nt) {
        if (nt < ntlo) continue;
        int krow = kstart + nt * 16 + frow;
        if (krow < 0) krow = 0;
        const _Float16* kp = Kb + (size_t)krow * HDIM + fcol;
#pragma unroll
        for (int ks = 0; ks < 4; ++ks) {
            f16x8 bk = *(const f16x8*)(kp + ks * 32);
            accs[nt] = __builtin_amdgcn_mfma_f32_16x16x32_f16(aq[ks], bk, accs[nt], 0, 0, 0);
        }
    }

    // ---- mask + scale; row max ----
    const int qrow = fgrp * 4;
    const int qabs = q0 + wv * 16 + qrow;
    const float scale = 0.08838834764831845f;
    float mx[4] = {-INFINITY, -INFINITY, -INFINITY, -INFINITY};
#pragma unroll
    for (int nt = 0; nt < NT; ++nt) {
        int key = kstart + nt * 16 + frow;
#pragma unroll
        for (int r = 0; r < 4; ++r) {
            int rel = (qabs + r) - key;
            bool keep = (key >= 0) && (rel >= 0) && (rel < w);
            float s = keep ? accs[nt][r] * scale : -INFINITY;
            accs[nt][r] = s;
            mx[r] = fmaxf(mx[r], s);
        }
    }
#pragma unroll
    for (int r = 0; r < 4; ++r) {
        float m = mx[r];
#pragma unroll
        for (int off = 1; off < 16; off <<= 1)
            m = fmaxf(m, __shfl_xor(m, off, 64));
        mx[r] = m;
    }

    // ---- exp, row sum, store P ----
    float ls[4] = {0.f, 0.f, 0.f, 0.f};
#pragma unroll
    for (int nt = 0; nt < NT; ++nt) {
#pragma unroll
        for (int r = 0; r < 4; ++r) {
            float p = __expf(accs[nt][r] - mx[r]);
            ls[r] += p;
            Pw[(qrow + r) * PSTR + nt * 16 + frow] = (_Float16)p;
        }
    }
    float inv[4];
#pragma unroll
    for (int r = 0; r < 4; ++r) {
        float l = ls[r];
#pragma unroll
        for (int off = 1; off < 16; off <<= 1)
            l += __shfl_xor(l, off, 64);
        inv[r] = 1.f / l;
    }

    // ---- PV ----
    const int pvlo = ntlo >> 1;
    f32x4 acco[8];
#pragma unroll
    for (int jt = 0; jt < 8; ++jt) acco[jt] = (f32x4){0.f, 0.f, 0.f, 0.f};
    const _Float16* Pr = &Pl[wv][frow * PSTR];
#pragma unroll
    for (int kp = 0; kp < 10; ++kp) {
        if (kp < pvlo) continue;
        f16x8 ap = *(const f16x8*)(Pr + kp * 32 + fcol);
        int kv = kstart + kp * 32 + fcol;
        if (kv < 0) kv = 0;
#pragma unroll
        for (int jt = 0; jt < 8; ++jt) {
            f16x8 bv = *(const f16x8*)(Vt + (size_t)(jt * 16 + frow) * S_LEN + kv);
            acco[jt] = __builtin_amdgcn_mfma_f32_16x16x32_f16(ap, bv, acco[jt], 0, 0, 0);
        }
    }

    // ---- store O (b, s, h*128+d) f16 ----
#pragma unroll
    for (int jt = 0; jt < 8; ++jt) {
#pragma unroll
        for (int r = 0; r < 4; ++r) {
            int s = qabs + r;
            ob[((size_t)b * S_LEN + s) * EMB + h * HDIM + jt * 16 + frow] =
                (_Float16)(acco[jt][r] * inv[r]);
        }
    }
}

// ---------------------------------------------------------------------------
extern "C" void kernel_launch(void* const* d_in, const int* in_sizes, int n_in,
                              void* d_out, int out_size, void* d_ws, size_t ws_size,
                              hipStream_t stream) {
    const float* x     = (const float*)d_in[0];
    const float* w_qkv = (const float*)d_in[1];
    const float* w_out = (const float*)d_in[2];
    const float* w_c1  = (const float*)d_in[3];
    const float* w_c2  = (const float*)d_in[4];
    float* out = (float*)d_out;
    char* ws = (char*)d_ws;

    // ws layout (bytes). ao16 aliases wqkv16 (dead after gemm_qkv).
    double*    scal   = (double*)(ws + 0);
    int*       win    = (int*)(ws + 64);
    float*     xmean  = (float*)(ws + 128);
    float*     hidden = (float*)(ws + 16640);
    float2*    cstab  = (float2*)(ws + 32768);       // 2 MB
    _Float16*  x16    = (_Float16*)(ws + 4194304);   // 16.8 MB
    _Float16*  wqkv16 = (_Float16*)(ws + 20971520);  // 25.2 MB
    _Float16*  ao16   = (_Float16*)(ws + 20971520);  // alias
    _Float16*  v16t   = (_Float16*)(ws + 46137344);  // 16.8 MB
    _Float16*  q16    = (_Float16*)(ws + 62914560);  // 16.8 MB
    _Float16*  k16    = (_Float16*)(ws + 79691776);  // 16.8 MB
    _Float16*  wout16 = (_Float16*)(ws + 96468992);  // 8.4 MB

    hipMemsetAsync(d_ws, 0, 32768, stream);

    rope_table<<<dim3(S_LEN), dim3(HDIM), 0, stream>>>(cstab);
    col_reduce<<<dim3(2, 64, 2), dim3(256), 0, stream>>>(x, xmean, scal, x16);
    hidden_kernel<<<dim3(512, 2), dim3(256), 0, stream>>>(xmean, w_c1, hidden);
    window_kernel<<<dim3(1), dim3(512), 0, stream>>>(hidden, w_c2, scal, win);

    cvt_weights<<<dim3((NQKV4 + NOUT4) / 256), dim3(256), 0, stream>>>(
        w_qkv, w_out, wqkv16, wout16);

    gemm_qkv_f16<<<dim3(48, 16), dim3(512), 0, stream>>>(x16, wqkv16, q16, k16, v16t, cstab);
    attn_mfma<<<dim3(32, HEADS, 2), dim3(256), 0, stream>>>(q16, k16, v16t, ao16, win);
    gemm_out_f16<<<dim3(16, 16), dim3(512), 0, stream>>>(ao16, wout16, out);
}

// Round 3
// 397.327 us; speedup vs baseline: 1.0346x; 1.0346x over previous
//
#include <hip/hip_runtime.h>
#include <math.h>

// ---------------------------------------------------------------------------
// AdaptiveWindowAttention — round 8 (resubmit; prior bench was an infra
// failure): GEMM core = proven round-6 (BK=64, xor-swizzled LDS, 128x128
// tile, 2-phase loop). Attention: exact per-wave tile bounds — wave wv only
// touches nt in [max(lo_w+wv, lo_n), wv+17); P zero-filled over the PV-read
// span; PV kp-range trimmed per wave. Cuts ~25% of QK^T and ~10% of PV work.
// B=2 S=2048 EMB=2048 H=16 D=128; window in [64,256]
// ---------------------------------------------------------------------------

#define S_LEN 2048
#define EMB 2048
#define HEADS 16
#define HDIM 128
#define NT 20          // 320-key span = NT*16
#define PSTR 336       // P row stride in f16 (320 + 16 pad -> conflict-free)

typedef _Float16 f16x8 __attribute__((ext_vector_type(8)));
typedef _Float16 f16x4 __attribute__((ext_vector_type(4)));
typedef float f32x4 __attribute__((ext_vector_type(4)));

__device__ __forceinline__ void gld16(const void* g, void* l) {
    __builtin_amdgcn_global_load_lds(
        (const __attribute__((address_space(1))) unsigned int*)g,
        (__attribute__((address_space(3))) unsigned int*)l, 16, 0, 0);
}

// ---------------- rope tables (cos,sin interleaved) ----------------
__global__ void rope_table(float2* __restrict__ cstab) {
    int s = blockIdx.x;
    int d = threadIdx.x;
    int j = d & 63;
    double inv = pow(10000.0, -(double)j / 64.0);
    double ang = (double)s * inv;
    cstab[s * HDIM + d] = make_float2((float)cos(ang), (float)sin(ang));
}

// ---------------- batch stats + fused x->f16 (float4, 4 cols/thread) --------
__global__ __launch_bounds__(256) void col_reduce(const float* __restrict__ x,
                                                  float* __restrict__ xmean_acc,
                                                  double* __restrict__ scal,
                                                  _Float16* __restrict__ x16) {
    int b = blockIdx.z;
    int cg = blockIdx.x;     // 2 column groups of 1024
    int sg = blockIdx.y;     // 64 row chunks of 32
    int e4 = cg * 256 + threadIdx.x;          // float4 column index
    const size_t base = ((size_t)b * S_LEN + sg * 32) * EMB;
    const float4* xb = (const float4*)(x + base) + e4;
    f16x4* xo = (f16x4*)(x16 + base) + e4;
    double cs0 = 0.0, cs1 = 0.0, cs2 = 0.0, cs3 = 0.0;
    double cq = 0.0;
    for (int s = 0; s < 32; ++s) {
        float4 v = xb[(size_t)s * (EMB / 4)];
        f16x4 o;
        o.x = (_Float16)v.x; o.y = (_Float16)v.y;
        o.z = (_Float16)v.z; o.w = (_Float16)v.w;
        xo[(size_t)s * (EMB / 4)] = o;
        cs0 += v.x; cs1 += v.y; cs2 += v.z; cs3 += v.w;
        cq += (double)v.x * v.x + (double)v.y * v.y +
              (double)v.z * v.z + (double)v.w * v.w;
    }
    float* xm = xmean_acc + b * EMB + e4 * 4;
    atomicAdd(xm + 0, (float)cs0);
    atomicAdd(xm + 1, (float)cs1);
    atomicAdd(xm + 2, (float)cs2);
    atomicAdd(xm + 3, (float)cs3);
    __shared__ double rs[256], rq[256];
    rs[threadIdx.x] = cs0 + cs1 + cs2 + cs3;
    rq[threadIdx.x] = cq;
    __syncthreads();
    for (int off = 128; off > 0; off >>= 1) {
        if (threadIdx.x < off) {
            rs[threadIdx.x] += rs[threadIdx.x + off];
            rq[threadIdx.x] += rq[threadIdx.x + off];
        }
        __syncthreads();
    }
    if (threadIdx.x == 0) {
        atomicAdd(&scal[b], rs[0]);
        atomicAdd(&scal[2 + b], rq[0]);
    }
}

__global__ __launch_bounds__(256) void hidden_kernel(const float* __restrict__ xmean_acc,
                                                     const float* __restrict__ wc1,
                                                     float* __restrict__ hidden) {
    int j = blockIdx.x;
    int b = blockIdx.y;
    const float* xm = xmean_acc + b * EMB;
    const float* wr = wc1 + (size_t)j * EMB;
    double acc = 0.0;
    for (int k = threadIdx.x; k < EMB; k += 256)
        acc += (double)xm[k] * (double)wr[k];
    __shared__ double red[256];
    red[threadIdx.x] = acc;
    __syncthreads();
    for (int off = 128; off > 0; off >>= 1) {
        if (threadIdx.x < off) red[threadIdx.x] += red[threadIdx.x + off];
        __syncthreads();
    }
    if (threadIdx.x == 0) {
        double z = red[0] * (1.0 / 2048.0);
        hidden[b * 512 + j] = (float)(z / (1.0 + exp(-z)));
    }
}

__global__ __launch_bounds__(512) void window_kernel(const float* __restrict__ hidden,
                                                     const float* __restrict__ wc2,
                                                     const double* __restrict__ scal,
                                                     int* __restrict__ wout) {
    __shared__ double red[512];
    __shared__ double wfs[2];
    for (int b = 0; b < 2; ++b) {
        red[threadIdx.x] = (double)hidden[b * 512 + threadIdx.x] * (double)wc2[threadIdx.x];
        __syncthreads();
        for (int off = 256; off > 0; off >>= 1) {
            if (threadIdx.x < off) red[threadIdx.x] += red[threadIdx.x + off];
            __syncthreads();
        }
        if (threadIdx.x == 0) {
            double pre = red[0];
            double learned = 1.0 / (1.0 + exp(-pre));
            const double N = (double)S_LEN * (double)EMB;
            double sum = scal[b], sq = scal[2 + b];
            double var = (sq - sum * sum / N) / (N - 1.0);
            double vn = 1.0 / (1.0 + exp(-(var * 10.0 - 5.0)));
            double comp = 0.5 * (vn + learned);
            wfs[b] = 64.0 + comp * 192.0;
        }
        __syncthreads();
    }
    if (threadIdx.x == 0) {
        float wf = (float)(0.5 * (wfs[0] + wfs[1]));
        int w = (int)wf;
        if (w > S_LEN) w = S_LEN;
        if (w < 64) w = 64;
        *wout = w;
    }
}

// ---------------- f32 -> f16 conversion (both weights, one launch) ----------
#define NQKV4 3145728   // 3*2048*2048/4
#define NOUT4 1048576   // 2048*2048/4
__global__ __launch_bounds__(256) void cvt_weights(const float* __restrict__ wqkv,
                                                   const float* __restrict__ wout,
                                                   _Float16* __restrict__ d_qkv,
                                                   _Float16* __restrict__ d_out) {
    int i = blockIdx.x * 256 + threadIdx.x;
    const float4* s;
    f16x4* d;
    if (i < NQKV4) {
        s = (const float4*)wqkv + i;
        d = (f16x4*)d_qkv + i;
    } else {
        s = (const float4*)wout + (i - NQKV4);
        d = (f16x4*)d_out + (i - NQKV4);
    }
    float4 v = *s;
    f16x4 o;
    o.x = (_Float16)v.x; o.y = (_Float16)v.y;
    o.z = (_Float16)v.z; o.w = (_Float16)v.w;
    *d = o;
}

// ---------------- MFMA GEMM core (BK=64, swizzled LDS) ----------------
#define GEMM_PROLOGUE(An, Wn)                                                   \
    __shared__ _Float16 As[128 * 64];                                           \
    __shared__ _Float16 Bs[128 * 64];                                           \
    const int tid = threadIdx.x;                                                \
    const int lane = tid & 63;                                                  \
    const int wv = tid >> 6;                                                    \
    const int wm = wv >> 1, wn = wv & 1;                                        \
    const int m0 = blockIdx.y * 128;                                            \
    const int n0 = blockIdx.x * 128;                                            \
    const int lrow = lane >> 3;                            /* 0..7 */           \
    const int lchk = (lane & 7) ^ lrow;                    /* swizzled src */   \
    const int srow = wv * 32 + lrow;                                            \
    const _Float16* agp = An + (size_t)(m0 + srow) * EMB + lchk * 8;            \
    const _Float16* bgp = Wn + (size_t)(n0 + srow) * EMB + lchk * 8;            \
    _Float16* al = &As[wv * 32 * 64];                                           \
    _Float16* bl = &Bs[wv * 32 * 64];                                           \
    const int frow = lane & 15;                                                 \
    const int fgrp = lane >> 4;                                                 \
    f32x4 acc[4][4] = {};                                                       \
    for (int k0 = 0; k0 < EMB; k0 += 64) {                                      \
        __syncthreads();                                                        \
        _Pragma("unroll")                                                       \
        for (int t = 0; t < 4; ++t) {                                           \
            gld16(agp + (size_t)t * 8 * EMB, al + t * 8 * 64);                  \
            gld16(bgp + (size_t)t * 8 * EMB, bl + t * 8 * 64);                  \
        }                                                                       \
        agp += 64; bgp += 64;                                                   \
        __syncthreads();                                                        \
        _Pragma("unroll")                                                       \
        for (int ks = 0; ks < 2; ++ks) {                                        \
            f16x8 af[4], bf[4];                                                 \
            _Pragma("unroll")                                                   \
            for (int i = 0; i < 4; ++i)                                         \
                af[i] = *(const f16x8*)&As[(wm * 64 + i * 16 + frow) * 64 +     \
                                           (((ks * 4 + fgrp) ^ (frow & 7)) * 8)]; \
            _Pragma("unroll")                                                   \
            for (int j = 0; j < 4; ++j)                                         \
                bf[j] = *(const f16x8*)&Bs[(wn * 64 + j * 16 + frow) * 64 +     \
                                           (((ks * 4 + fgrp) ^ (frow & 7)) * 8)]; \
            _Pragma("unroll")                                                   \
            for (int i = 0; i < 4; ++i)                                         \
                _Pragma("unroll")                                               \
                for (int j = 0; j < 4; ++j)                                     \
                    acc[i][j] = __builtin_amdgcn_mfma_f32_16x16x32_f16(         \
                        af[i], bf[j], acc[i][j], 0, 0, 0);                      \
        }                                                                       \
    }                                                                           \
    const int colbase = lane & 15;                                              \
    const int rowoff = (lane >> 4) * 4;

// qkv epilogue: rope fused -> q16/k16 f16 (B,H,S,D); v -> f16 (B,H,D,S)
__global__ __launch_bounds__(256) void gemm_qkv_f16(const _Float16* __restrict__ An,
                                                    const _Float16* __restrict__ Wn,
                                                    _Float16* __restrict__ q16,
                                                    _Float16* __restrict__ k16,
                                                    _Float16* __restrict__ vt,
                                                    const float2* __restrict__ cstab) {
    GEMM_PROLOGUE(An, Wn)
    const int which = n0 >> 11;
    const int h = (n0 >> 7) & 15;
    if (which == 2) {
#pragma unroll
        for (int i = 0; i < 4; ++i) {
#pragma unroll
            for (int j = 0; j < 4; ++j) {
                const int d = wn * 64 + j * 16 + colbase;
                int m = m0 + wm * 64 + i * 16 + rowoff;  // 4 consecutive rows
                int b = m >> 11, s = m & 2047;
                f16x4 o;
#pragma unroll
                for (int r = 0; r < 4; ++r) o[r] = (_Float16)acc[i][j][r];
                *(f16x4*)&vt[(((size_t)b * HEADS + h) * HDIM + d) * S_LEN + s] = o;
            }
        }
    } else {
        _Float16* dst = which == 0 ? q16 : k16;
        const float sgn = (colbase & 1) ? 1.f : -1.f;   // rotate_half sign
#pragma unroll
        for (int i = 0; i < 4; ++i) {
#pragma unroll
            for (int j = 0; j < 4; ++j) {
                const int d = wn * 64 + j * 16 + colbase;
#pragma unroll
                for (int r = 0; r < 4; ++r) {
                    int m = m0 + wm * 64 + i * 16 + rowoff + r;
                    int b = m >> 11, s = m & 2047;
                    float a = acc[i][j][r];
                    float p = __shfl_xor(a, 1, 64);      // partner: d^1, same s
                    float2 cs = cstab[(size_t)s * HDIM + d];
                    float o = fmaf(a, cs.x, sgn * p * cs.y);
                    dst[(((size_t)b * HEADS + h) * S_LEN + s) * HDIM + d] = (_Float16)o;
                }
            }
        }
    }
}

__global__ __launch_bounds__(256) void gemm_out_f16(const _Float16* __restrict__ An,
                                                    const _Float16* __restrict__ Wn,
                                                    float* __restrict__ C) {
    GEMM_PROLOGUE(An, Wn)
#pragma unroll
    for (int i = 0; i < 4; ++i) {
#pragma unroll
        for (int j = 0; j < 4; ++j) {
            const int n = n0 + wn * 64 + j * 16 + colbase;
#pragma unroll
            for (int r = 0; r < 4; ++r) {
                int m = m0 + wm * 64 + i * 16 + rowoff + r;
                C[(size_t)m * EMB + n] = acc[i][j][r];
            }
        }
    }
}

// ---------------- MFMA attention (per-wave exact tile bounds) ----------------
__global__ __launch_bounds__(256) void attn_mfma(const _Float16* __restrict__ q16,
                                                 const _Float16* __restrict__ k16,
                                                 const _Float16* __restrict__ v16t,
                                                 _Float16* __restrict__ ob,
                                                 const int* __restrict__ wptr) {
    const int q0 = blockIdx.x * 64;
    const int h = blockIdx.y;
    const int b = blockIdx.z;
    const int tid = threadIdx.x;
    const int lane = tid & 63;
    const int wv = tid >> 6;
    const int w = *wptr;

    __shared__ _Float16 Pl[4][16 * PSTR];
    _Float16* Pw = Pl[wv];

    const int kstart = q0 - 256;
    // per-wave exact bounds: wave wv owns q-rows [q0+16wv, q0+16wv+15].
    // window lower bound: tile dead iff kstart+16nt+15 < q0+16wv-w+1
    //   -> lo_w = ((257-w)>>4) + wv
    // key>=0 bound (block-level): ntlo_n
    // causal upper bound: tile dead iff kstart+16nt > q0+16wv+15 -> nt >= wv+17
    int ntlo_w = ((257 - w) >> 4) + wv;
    int ntlo_n = q0 < 256 ? ((256 - q0) >> 4) : 0;
    const int lo = ntlo_w > ntlo_n ? ntlo_w : ntlo_n;
    const int hi = wv + 17;
    const int pvlo = lo >> 1;
    const int pvhi = (hi + 1) >> 1;
    const int plo2 = pvlo << 1;
    const int phi2 = pvhi << 1;

    const int frow = lane & 15;
    const int fgrp = lane >> 4;
    const int fcol = fgrp * 8;

    const size_t bh = (size_t)b * HEADS + h;
    const _Float16* Qp = q16 + (bh * S_LEN + q0 + wv * 16 + frow) * HDIM + fcol;
    const _Float16* Kb = k16 + bh * S_LEN * HDIM;
    const _Float16* Vt = v16t + bh * HDIM * S_LEN;

    f16x8 aq[4];
#pragma unroll
    for (int ks = 0; ks < 4; ++ks) aq[ks] = *(const f16x8*)(Qp + ks * 32);

    // ---- QK^T (only alive tiles) ----
    f32x4 accs[NT];
#pragma unroll
    for (int nt = 0; nt < NT; ++nt) accs[nt] = (f32x4){0.f, 0.f, 0.f, 0.f};
#pragma unroll
    for (int nt = 0; nt < NT; ++nt) {
        if (nt < lo || nt >= hi) continue;
        int krow = kstart + nt * 16 + frow;
        if (krow < 0) krow = 0;
        const _Float16* kp = Kb + (size_t)krow * HDIM + fcol;
#pragma unroll
        for (int ks = 0; ks < 4; ++ks) {
            f16x8 bk = *(const f16x8*)(kp + ks * 32);
            accs[nt] = __builtin_amdgcn_mfma_f32_16x16x32_f16(aq[ks], bk, accs[nt], 0, 0, 0);
        }
    }

    // ---- mask + scale; row max ----
    const int qrow = fgrp * 4;
    const int qabs = q0 + wv * 16 + qrow;
    const float scale = 0.08838834764831845f;
    float mx[4] = {-INFINITY, -INFINITY, -INFINITY, -INFINITY};
#pragma unroll
    for (int nt = 0; nt < NT; ++nt) {
        if (nt < lo || nt >= hi) continue;
        int key = kstart + nt * 16 + frow;
#pragma unroll
        for (int r = 0; r < 4; ++r) {
            int rel = (qabs + r) - key;
            bool keep = (key >= 0) && (rel >= 0) && (rel < w);
            float s = keep ? accs[nt][r] * scale : -INFINITY;
            accs[nt][r] = s;
            mx[r] = fmaxf(mx[r], s);
        }
    }
#pragma unroll
    for (int r = 0; r < 4; ++r) {
        float m = mx[r];
#pragma unroll
        for (int off = 1; off < 16; off <<= 1)
            m = fmaxf(m, __shfl_xor(m, off, 64));
        mx[r] = m;
    }

    // ---- exp, row sum, store P (zero-fill dead tiles within PV span) ----
    float ls[4] = {0.f, 0.f, 0.f, 0.f};
#pragma unroll
    for (int nt = 0; nt < NT; ++nt) {
        if (nt < plo2 || nt >= phi2) continue;
        const bool alive = (nt >= lo) && (nt < hi);
#pragma unroll
        for (int r = 0; r < 4; ++r) {
            float p = alive ? __expf(accs[nt][r] - mx[r]) : 0.f;
            ls[r] += p;
            Pw[(qrow + r) * PSTR + nt * 16 + frow] = (_Float16)p;
        }
    }
    float inv[4];
#pragma unroll
    for (int r = 0; r < 4; ++r) {
        float l = ls[r];
#pragma unroll
        for (int off = 1; off < 16; off <<= 1)
            l += __shfl_xor(l, off, 64);
        inv[r] = 1.f / l;
    }

    // ---- PV (only alive 32-key tiles) ----
    f32x4 acco[8];
#pragma unroll
    for (int jt = 0; jt < 8; ++jt) acco[jt] = (f32x4){0.f, 0.f, 0.f, 0.f};
    const _Float16* Pr = &Pl[wv][frow * PSTR];
#pragma unroll
    for (int kp = 0; kp < 10; ++kp) {
        if (kp < pvlo || kp >= pvhi) continue;
        f16x8 ap = *(const f16x8*)(Pr + kp * 32 + fcol);
        int kv = kstart + kp * 32 + fcol;
        if (kv < 0) kv = 0;
#pragma unroll
        for (int jt = 0; jt < 8; ++jt) {
            f16x8 bv = *(const f16x8*)(Vt + (size_t)(jt * 16 + frow) * S_LEN + kv);
            acco[jt] = __builtin_amdgcn_mfma_f32_16x16x32_f16(ap, bv, acco[jt], 0, 0, 0);
        }
    }

    // ---- store O (b, s, h*128+d) f16 ----
#pragma unroll
    for (int jt = 0; jt < 8; ++jt) {
#pragma unroll
        for (int r = 0; r < 4; ++r) {
            int s = qabs + r;
            ob[((size_t)b * S_LEN + s) * EMB + h * HDIM + jt * 16 + frow] =
                (_Float16)(acco[jt][r] * inv[r]);
        }
    }
}

// ---------------------------------------------------------------------------
extern "C" void kernel_launch(void* const* d_in, const int* in_sizes, int n_in,
                              void* d_out, int out_size, void* d_ws, size_t ws_size,
                              hipStream_t stream) {
    const float* x     = (const float*)d_in[0];
    const float* w_qkv = (const float*)d_in[1];
    const float* w_out = (const float*)d_in[2];
    const float* w_c1  = (const float*)d_in[3];
    const float* w_c2  = (const float*)d_in[4];
    float* out = (float*)d_out;
    char* ws = (char*)d_ws;

    // ws layout (bytes). ao16 aliases wqkv16 (dead after gemm_qkv).
    double*    scal   = (double*)(ws + 0);
    int*       win    = (int*)(ws + 64);
    float*     xmean  = (float*)(ws + 128);
    float*     hidden = (float*)(ws + 16640);
    float2*    cstab  = (float2*)(ws + 32768);       // 2 MB
    _Float16*  x16    = (_Float16*)(ws + 4194304);   // 16.8 MB
    _Float16*  wqkv16 = (_Float16*)(ws + 20971520);  // 25.2 MB
    _Float16*  ao16   = (_Float16*)(ws + 20971520);  // alias
    _Float16*  v16t   = (_Float16*)(ws + 46137344);  // 16.8 MB
    _Float16*  q16    = (_Float16*)(ws + 62914560);  // 16.8 MB
    _Float16*  k16    = (_Float16*)(ws + 79691776);  // 16.8 MB
    _Float16*  wout16 = (_Float16*)(ws + 96468992);  // 8.4 MB

    hipMemsetAsync(d_ws, 0, 32768, stream);

    rope_table<<<dim3(S_LEN), dim3(HDIM), 0, stream>>>(cstab);
    col_reduce<<<dim3(2, 64, 2), dim3(256), 0, stream>>>(x, xmean, scal, x16);
    hidden_kernel<<<dim3(512, 2), dim3(256), 0, stream>>>(xmean, w_c1, hidden);
    window_kernel<<<dim3(1), dim3(512), 0, stream>>>(hidden, w_c2, scal, win);

    cvt_weights<<<dim3((NQKV4 + NOUT4) / 256), dim3(256), 0, stream>>>(
        w_qkv, w_out, wqkv16, wout16);

    gemm_qkv_f16<<<dim3(48, 32), dim3(256), 0, stream>>>(x16, wqkv16, q16, k16, v16t, cstab);
    attn_mfma<<<dim3(32, HEADS, 2), dim3(256), 0, stream>>>(q16, k16, v16t, ao16, win);
    gemm_out_f16<<<dim3(16, 32), dim3(256), 0, stream>>>(ao16, wout16, out);
}